// Round 22
// baseline (212.682 us; speedup 1.0000x reference)
//
#include <hip/hip_runtime.h>
#include <hip/hip_bf16.h>

#define NN 8192
#define CC 256
// exp(x/0.01) = exp2(x * 100 * log2(e))
#define ESCALE 144.26950408889634f

typedef __attribute__((ext_vector_type(8))) short short8;
typedef __attribute__((ext_vector_type(4))) float f32x4;

typedef __attribute__((address_space(3))) unsigned int lds_u32;
typedef __attribute__((address_space(1))) const unsigned int glb_u32;

__device__ __forceinline__ void gload16(const ushort* g, ushort* l) {
  __builtin_amdgcn_global_load_lds((glb_u32*)(const void*)g, (lds_u32*)(void*)l, 16, 0, 0);
}

// ---------------- per-channel sum of squares (partials) ----------------
__global__ void colsumsq_kernel(const float* __restrict__ x, const float* __restrict__ y,
                                float* __restrict__ part) {
  const int b = blockIdx.x, t = threadIdx.x;
  const float* src = (b < 256) ? x : y;
  const int bb = b & 255;
  float s = 0.f;
#pragma unroll 4
  for (int r = 0; r < 32; ++r) {
    float v = src[(size_t)(bb * 32 + r) * CC + t];
    s = fmaf(v, v, s);
  }
  part[b * CC + t] = s;
}

// one wave per output norm: 512 outputs = 128 blocks x 4 waves
__global__ void finnorm_kernel(const float* __restrict__ part, float* __restrict__ inv_n) {
  const int g = blockIdx.x * 4 + (threadIdx.x >> 6);  // 0..511
  const int lane = threadIdx.x & 63;
  const int c = g & 255, T = g >> 8;
  float s = 0.f;
#pragma unroll
  for (int r = 0; r < 4; ++r)
    s += part[(size_t)((T << 8) + lane * 4 + r) * CC + c];
#pragma unroll
  for (int d = 1; d < 64; d <<= 1) s += __shfl_xor(s, d);
  if (lane == 0) inv_n[g] = 1.0f / sqrtf(s);
}

// ---------------- normalize + convert to bf16 (x and y fused) ----------------
__global__ void normconv_kernel(const float* __restrict__ x, const float* __restrict__ y,
                                const float* __restrict__ inv_n,
                                ushort* __restrict__ xnb, ushort* __restrict__ ynb) {
  int b = blockIdx.x;
  const float* src; ushort* dst; const float* inv;
  if (b < 2048) { src = x; dst = xnb; inv = inv_n; }
  else          { src = y; dst = ynb; inv = inv_n + 256; b -= 2048; }
  const int idx = (b * 256 + threadIdx.x) * 4;
  const float4 v = *(const float4*)(src + idx);
  const int c = idx & (CC - 1);
  __hip_bfloat16 h0 = __float2bfloat16(v.x * inv[c + 0]);
  __hip_bfloat16 h1 = __float2bfloat16(v.y * inv[c + 1]);
  __hip_bfloat16 h2 = __float2bfloat16(v.z * inv[c + 2]);
  __hip_bfloat16 h3 = __float2bfloat16(v.w * inv[c + 3]);
  ushort4 o;
  o.x = *(ushort*)&h0; o.y = *(ushort*)&h1; o.z = *(ushort*)&h2; o.w = *(ushort*)&h3;
  *(ushort4*)(dst + idx) = o;
}

// ---------------- main GEMM + fused epilogue ----------------
// 256x128 tile, 8 waves (4x2), BK=64, 512 threads, mfma_f32_16x16x32_bf16.
// Same proven skeleton as r16 (2-barrier loop, slot-XOR swizzle, 0 conflicts)
// but bigger tile: LDS 48KB -> 3 blocks/CU = 24 waves/CU (was 16) and 1.33x
// compute per staged byte; MFMA-per-barrier doubles. launch_bounds(512,6):
// VGPR cap ~84 > ~64 needed -> no spill (r15 lesson).
// Swizzle: phys 16B-slot = logical_slot ^ (row&7); all read row-bases are
// multiples of 8 so row&7 == lr&7; staging permute r-independent (64%8==0).
__global__ __launch_bounds__(512, 6)
void gemm_corr_kernel(const ushort* __restrict__ Xn, const ushort* __restrict__ Yn,
                      float* __restrict__ corr_top,     // [256][NN]
                      float* __restrict__ rowmax_part,  // [64][NN]  idx cb*NN + i
                      float* __restrict__ colsum_part)  // [32][NN]  idx rb*NN + j
{
  const int cb = blockIdx.x, rb = blockIdx.y;   // cb: 64 col-tiles, rb: 32 row-tiles
  const int tid = threadIdx.x;
  const int lane = tid & 63, wid = tid >> 6;    // 8 waves
  const int wr = wid >> 1, wc = wid & 1;        // 4x2 wave grid, wave tile 64x64
  const int q = lane >> 4;    // k-group selector
  const int lr = lane & 15;

  __shared__ __align__(16) ushort As[256 * 64];   // 32 KB, slot-swizzled
  __shared__ __align__(16) ushort Bs[128 * 64];   // 16 KB
  float* redmax = (float*)As;                     // [2][256] aliased (dead post-K)
  float* redsum = (float*)As + 512;               // [4][128]

  f32x4 acc[4][4];
#pragma unroll
  for (int m = 0; m < 4; ++m)
#pragma unroll
    for (int n = 0; n < 4; ++n) acc[m][n] = (f32x4){0.f, 0.f, 0.f, 0.f};

  // staging: granule g = r*512 + tid (16B); row = g>>3 = r*64 + (tid>>3),
  // phys slot p = tid&7 holds logical slot p ^ (row&7) -> source pre-permuted.
  const int srow0 = tid >> 3;                    // 0..63
  const int sp = (tid & 7) ^ (srow0 & 7);
  const size_t gAb = (size_t)(rb * 256 + srow0) * CC + sp * 8;
  const size_t gBb = (size_t)(cb * 128 + srow0) * CC + sp * 8;

  auto stage = [&](int kt) {
    const int ko = kt * 64;
#pragma unroll
    for (int r = 0; r < 4; ++r)
      gload16(Xn + gAb + r * 64 * CC + ko, &As[r * 4096 + wid * 512]);
#pragma unroll
    for (int r = 0; r < 2; ++r)
      gload16(Yn + gBb + r * 64 * CC + ko, &Bs[r * 4096 + wid * 512]);
  };

  for (int kt = 0; kt < 4; ++kt) {
    stage(kt);
    __syncthreads();   // DMA resident
#pragma unroll
    for (int s = 0; s < 2; ++s) {
      const int sA = ((s * 4 + q) ^ (lr & 7)) * 8;   // swizzled k-slot
      short8 af[4], bf[4];
#pragma unroll
      for (int m = 0; m < 4; ++m)
        af[m] = *(const short8*)(&As[(wr * 64 + m * 16 + lr) * 64 + sA]);
#pragma unroll
      for (int n = 0; n < 4; ++n)
        bf[n] = *(const short8*)(&Bs[(wc * 64 + n * 16 + lr) * 64 + sA]);
#pragma unroll
      for (int m = 0; m < 4; ++m)
#pragma unroll
        for (int n = 0; n < 4; ++n)
          acc[m][n] = __builtin_amdgcn_mfma_f32_16x16x32_bf16(af[m], bf[n], acc[m][n], 0, 0, 0);
    }
    __syncthreads();   // reads done before next stage overwrites
  }

  // ---- store top-256 corr rows for the warped pass (rb==0 covers rows 0..255) ----
  if (rb == 0) {
    const int colg = cb * 128 + wc * 64 + lr;
#pragma unroll
    for (int m = 0; m < 4; ++m) {
      const int rowg = wr * 64 + m * 16 + q * 4;
#pragma unroll
      for (int n = 0; n < 4; ++n)
#pragma unroll
        for (int r = 0; r < 4; ++r)
          corr_top[(size_t)(rowg + r) * NN + colg + n * 16] = acc[m][n][r];
    }
  }

  // ---- row max over this block's 128 columns (256 rows) ----
  // C/D layout: col = n*16 + (lane&15); row = m*16 + (lane>>4)*4 + r
#pragma unroll
  for (int m = 0; m < 4; ++m)
#pragma unroll
    for (int r = 0; r < 4; ++r) {
      float t = fmaxf(fmaxf(acc[m][0][r], acc[m][1][r]), fmaxf(acc[m][2][r], acc[m][3][r]));
      t = fmaxf(t, __shfl_xor(t, 1));
      t = fmaxf(t, __shfl_xor(t, 2));
      t = fmaxf(t, __shfl_xor(t, 4));
      t = fmaxf(t, __shfl_xor(t, 8));
      if (lr == 0) redmax[wc * 256 + wr * 64 + m * 16 + q * 4 + r] = t;
    }
  __syncthreads();
  if (tid < 256)
    rowmax_part[(size_t)cb * NN + rb * 256 + tid] = fmaxf(redmax[tid], redmax[256 + tid]);
  __syncthreads();

  // ---- column sum of exp(corr/tau) over this block's 256 rows ----
#pragma unroll
  for (int n = 0; n < 4; ++n) {
    float s = 0.f;
#pragma unroll
    for (int m = 0; m < 4; ++m)
#pragma unroll
      for (int r = 0; r < 4; ++r)
        s += __builtin_amdgcn_exp2f(acc[m][n][r] * ESCALE);
    s += __shfl_xor(s, 16);
    s += __shfl_xor(s, 32);
    if (lane < 16) redsum[wr * 128 + wc * 64 + n * 16 + lr] = s;
  }
  __syncthreads();
  if (tid < 128)
    colsum_part[(size_t)rb * NN + cb * 128 + tid] =
        redsum[tid] + redsum[128 + tid] + redsum[256 + tid] + redsum[384 + tid];
}

// ---------------- fused reductions: thread per output, coalesced ----------------
__global__ void reduce_both_kernel(const float* __restrict__ rowmax_part,
                                   const float* __restrict__ colsum_part,
                                   float* __restrict__ out, float* __restrict__ inv_s) {
  const int g = blockIdx.x * 256 + threadIdx.x;   // [0, 16384)
  if (g < 8192) {
    float m = -3.4e38f;
#pragma unroll
    for (int b = 0; b < 64; ++b) m = fmaxf(m, rowmax_part[(size_t)b * NN + g]);
    out[256 + g] = m;
  } else {
    const int j = g - 8192;
    float s = 0.f;
#pragma unroll
    for (int b = 0; b < 32; ++b) s += colsum_part[(size_t)b * NN + j];
    inv_s[j] = 1.0f / s;
  }
}

// ---------------- warped color partials ----------------
// 128 blocks = 32 k-octets x 4 j-quarters. Thread t: kk = t&7, j-stream t>>3.
// 8 adjacent lanes share j -> ynb reads are 16B-contiguous per 8 lanes.
__global__ void warped_kernel(const float* __restrict__ corr_top, const float* __restrict__ inv_s,
                              const ushort* __restrict__ ynb, float* __restrict__ wpart) {
  const int b = blockIdx.x;
  const int kb = b & 31, jb = b >> 5;
  const int k0 = kb * 8;
  const int t = threadIdx.x;
  const int kk = t & 7, js = t >> 3;     // js 0..31
  const int jbase = jb * 2048 + js;
  float p = 0.f;
#pragma unroll 4
  for (int i = 0; i < 64; ++i) {
    const int j = jbase + 32 * i;
    float c = corr_top[(size_t)(k0 + kk) * NN + j];
    float yv = __uint_as_float((unsigned)ynb[(size_t)j * CC + k0 + kk] << 16);
    p += __builtin_amdgcn_exp2f(c * ESCALE) * inv_s[j] * yv;
  }
  // reduce the 8 j-streams within each wave (kk preserved: masks 8,16,32)
  p += __shfl_xor(p, 8);
  p += __shfl_xor(p, 16);
  p += __shfl_xor(p, 32);
  __shared__ float lw[4][8];
  const int lane = t & 63, wid = t >> 6;
  if (lane < 8) lw[wid][lane] = p;
  __syncthreads();
  if (t < 8) wpart[jb * 256 + k0 + t] = lw[0][t] + lw[1][t] + lw[2][t] + lw[3][t];
}

__global__ void warpedfin_kernel(const float* __restrict__ wpart, float* __restrict__ out) {
  const int k = threadIdx.x;
  out[k] = wpart[k] + wpart[256 + k] + wpart[512 + k] + wpart[768 + k];
}

extern "C" void kernel_launch(void* const* d_in, const int* in_sizes, int n_in,
                              void* d_out, int out_size, void* d_ws, size_t ws_size,
                              hipStream_t stream) {
  const float* x = (const float*)d_in[0];
  const float* y = (const float*)d_in[1];
  float* out = (float*)d_out;
  char* ws = (char*)d_ws;

  ushort* xnb        = (ushort*)(ws);                        // 4 MB
  ushort* ynb        = (ushort*)(ws + (4u << 20));           // 4 MB
  float*  corr_top   = (float*)(ws + (8u << 20));            // 8 MB
  float*  rowmax_prt = (float*)(ws + (16u << 20));           // 2 MB
  float*  colsum_prt = (float*)(ws + (18u << 20));           // 1 MB
  float*  part       = (float*)(ws + (20u << 20));           // 512 KB (reused as wpart)
  float*  inv_n      = (float*)(ws + (20u << 20) + 524288);  // 2 KB
  float*  inv_s      = (float*)(ws + (20u << 20) + 524288 + 4096); // 32 KB

  colsumsq_kernel<<<512, 256, 0, stream>>>(x, y, part);
  finnorm_kernel<<<128, 256, 0, stream>>>(part, inv_n);
  normconv_kernel<<<4096, 256, 0, stream>>>(x, y, inv_n, xnb, ynb);
  gemm_corr_kernel<<<dim3(64, 32), 512, 0, stream>>>(xnb, ynb, corr_top, rowmax_prt, colsum_prt);
  reduce_both_kernel<<<64, 256, 0, stream>>>(rowmax_prt, colsum_prt, out, inv_s);
  warped_kernel<<<128, 256, 0, stream>>>(corr_top, inv_s, ynb, part);
  warpedfin_kernel<<<1, 256, 0, stream>>>(part, out);
}

// Round 23
// 76.593 us; speedup vs baseline: 2.7768x; 2.7768x over previous
//
#include <hip/hip_runtime.h>
#include <hip/hip_bf16.h>

#define NN 8192
#define CC 256
// exp(x/0.01) = exp2(x * 100 * log2(e))
#define ESCALE 144.26950408889634f

typedef __attribute__((ext_vector_type(8))) short short8;
typedef __attribute__((ext_vector_type(4))) float f32x4;

typedef __attribute__((address_space(3))) unsigned int lds_u32;
typedef __attribute__((address_space(1))) const unsigned int glb_u32;

__device__ __forceinline__ void gload16(const ushort* g, ushort* l) {
  __builtin_amdgcn_global_load_lds((glb_u32*)(const void*)g, (lds_u32*)(void*)l, 16, 0, 0);
}

// ---------------- per-channel sum of squares (partials) ----------------
__global__ void colsumsq_kernel(const float* __restrict__ x, const float* __restrict__ y,
                                float* __restrict__ part) {
  const int b = blockIdx.x, t = threadIdx.x;
  const float* src = (b < 256) ? x : y;
  const int bb = b & 255;
  float s = 0.f;
#pragma unroll 4
  for (int r = 0; r < 32; ++r) {
    float v = src[(size_t)(bb * 32 + r) * CC + t];
    s = fmaf(v, v, s);
  }
  part[b * CC + t] = s;
}

// one wave per output norm: 512 outputs = 128 blocks x 4 waves
__global__ void finnorm_kernel(const float* __restrict__ part, float* __restrict__ inv_n) {
  const int g = blockIdx.x * 4 + (threadIdx.x >> 6);  // 0..511
  const int lane = threadIdx.x & 63;
  const int c = g & 255, T = g >> 8;
  float s = 0.f;
#pragma unroll
  for (int r = 0; r < 4; ++r)
    s += part[(size_t)((T << 8) + lane * 4 + r) * CC + c];
#pragma unroll
  for (int d = 1; d < 64; d <<= 1) s += __shfl_xor(s, d);
  if (lane == 0) inv_n[g] = 1.0f / sqrtf(s);
}

// ---------------- normalize + convert to bf16 (x and y fused) ----------------
__global__ void normconv_kernel(const float* __restrict__ x, const float* __restrict__ y,
                                const float* __restrict__ inv_n,
                                ushort* __restrict__ xnb, ushort* __restrict__ ynb) {
  int b = blockIdx.x;
  const float* src; ushort* dst; const float* inv;
  if (b < 2048) { src = x; dst = xnb; inv = inv_n; }
  else          { src = y; dst = ynb; inv = inv_n + 256; b -= 2048; }
  const int idx = (b * 256 + threadIdx.x) * 4;
  const float4 v = *(const float4*)(src + idx);
  const int c = idx & (CC - 1);
  __hip_bfloat16 h0 = __float2bfloat16(v.x * inv[c + 0]);
  __hip_bfloat16 h1 = __float2bfloat16(v.y * inv[c + 1]);
  __hip_bfloat16 h2 = __float2bfloat16(v.z * inv[c + 2]);
  __hip_bfloat16 h3 = __float2bfloat16(v.w * inv[c + 3]);
  ushort4 o;
  o.x = *(ushort*)&h0; o.y = *(ushort*)&h1; o.z = *(ushort*)&h2; o.w = *(ushort*)&h3;
  *(ushort4*)(dst + idx) = o;
}

// ---------------- main GEMM + fused epilogue ----------------
// 256x128 tile, 8 waves (4x2), BK=64, 512 threads, mfma_f32_16x16x32_bf16.
// Same proven skeleton as r16 (2-barrier loop, slot-XOR swizzle, 0 conflicts)
// with bigger tile: LDS 48KB -> 3 blocks/CU = 24 waves/CU and 1.33x compute
// per staged byte; MFMA-per-barrier doubles.
// launch_bounds(512,2): r22's (512,6) capped VGPR at 40 < 64-float acc ->
// spills (FETCH 272MB, gemm 190us). Min-2 leaves the allocator free; the HW
// still co-schedules 3 blocks/CU by LDS on its own.
// Swizzle: phys 16B-slot = logical_slot ^ (row&7); all read row-bases are
// multiples of 8 so row&7 == lr&7; staging permute r-independent (64%8==0).
__global__ __launch_bounds__(512, 2)
void gemm_corr_kernel(const ushort* __restrict__ Xn, const ushort* __restrict__ Yn,
                      float* __restrict__ corr_top,     // [256][NN]
                      float* __restrict__ rowmax_part,  // [64][NN]  idx cb*NN + i
                      float* __restrict__ colsum_part)  // [32][NN]  idx rb*NN + j
{
  const int cb = blockIdx.x, rb = blockIdx.y;   // cb: 64 col-tiles, rb: 32 row-tiles
  const int tid = threadIdx.x;
  const int lane = tid & 63, wid = tid >> 6;    // 8 waves
  const int wr = wid >> 1, wc = wid & 1;        // 4x2 wave grid, wave tile 64x64
  const int q = lane >> 4;    // k-group selector
  const int lr = lane & 15;

  __shared__ __align__(16) ushort As[256 * 64];   // 32 KB, slot-swizzled
  __shared__ __align__(16) ushort Bs[128 * 64];   // 16 KB
  float* redmax = (float*)As;                     // [2][256] aliased (dead post-K)
  float* redsum = (float*)As + 512;               // [4][128]

  f32x4 acc[4][4];
#pragma unroll
  for (int m = 0; m < 4; ++m)
#pragma unroll
    for (int n = 0; n < 4; ++n) acc[m][n] = (f32x4){0.f, 0.f, 0.f, 0.f};

  // staging: granule g = r*512 + tid (16B); row = g>>3 = r*64 + (tid>>3),
  // phys slot p = tid&7 holds logical slot p ^ (row&7) -> source pre-permuted.
  const int srow0 = tid >> 3;                    // 0..63
  const int sp = (tid & 7) ^ (srow0 & 7);
  const size_t gAb = (size_t)(rb * 256 + srow0) * CC + sp * 8;
  const size_t gBb = (size_t)(cb * 128 + srow0) * CC + sp * 8;

  auto stage = [&](int kt) {
    const int ko = kt * 64;
#pragma unroll
    for (int r = 0; r < 4; ++r)
      gload16(Xn + gAb + r * 64 * CC + ko, &As[r * 4096 + wid * 512]);
#pragma unroll
    for (int r = 0; r < 2; ++r)
      gload16(Yn + gBb + r * 64 * CC + ko, &Bs[r * 4096 + wid * 512]);
  };

  for (int kt = 0; kt < 4; ++kt) {
    stage(kt);
    __syncthreads();   // DMA resident
#pragma unroll
    for (int s = 0; s < 2; ++s) {
      const int sA = ((s * 4 + q) ^ (lr & 7)) * 8;   // swizzled k-slot
      short8 af[4], bf[4];
#pragma unroll
      for (int m = 0; m < 4; ++m)
        af[m] = *(const short8*)(&As[(wr * 64 + m * 16 + lr) * 64 + sA]);
#pragma unroll
      for (int n = 0; n < 4; ++n)
        bf[n] = *(const short8*)(&Bs[(wc * 64 + n * 16 + lr) * 64 + sA]);
#pragma unroll
      for (int m = 0; m < 4; ++m)
#pragma unroll
        for (int n = 0; n < 4; ++n)
          acc[m][n] = __builtin_amdgcn_mfma_f32_16x16x32_bf16(af[m], bf[n], acc[m][n], 0, 0, 0);
    }
    __syncthreads();   // reads done before next stage overwrites
  }

  // ---- store top-256 corr rows for the warped pass (rb==0 covers rows 0..255) ----
  if (rb == 0) {
    const int colg = cb * 128 + wc * 64 + lr;
#pragma unroll
    for (int m = 0; m < 4; ++m) {
      const int rowg = wr * 64 + m * 16 + q * 4;
#pragma unroll
      for (int n = 0; n < 4; ++n)
#pragma unroll
        for (int r = 0; r < 4; ++r)
          corr_top[(size_t)(rowg + r) * NN + colg + n * 16] = acc[m][n][r];
    }
  }

  // ---- row max over this block's 128 columns (256 rows) ----
  // C/D layout: col = n*16 + (lane&15); row = m*16 + (lane>>4)*4 + r
#pragma unroll
  for (int m = 0; m < 4; ++m)
#pragma unroll
    for (int r = 0; r < 4; ++r) {
      float t = fmaxf(fmaxf(acc[m][0][r], acc[m][1][r]), fmaxf(acc[m][2][r], acc[m][3][r]));
      t = fmaxf(t, __shfl_xor(t, 1));
      t = fmaxf(t, __shfl_xor(t, 2));
      t = fmaxf(t, __shfl_xor(t, 4));
      t = fmaxf(t, __shfl_xor(t, 8));
      if (lr == 0) redmax[wc * 256 + wr * 64 + m * 16 + q * 4 + r] = t;
    }
  __syncthreads();
  if (tid < 256)
    rowmax_part[(size_t)cb * NN + rb * 256 + tid] = fmaxf(redmax[tid], redmax[256 + tid]);
  __syncthreads();

  // ---- column sum of exp(corr/tau) over this block's 256 rows ----
#pragma unroll
  for (int n = 0; n < 4; ++n) {
    float s = 0.f;
#pragma unroll
    for (int m = 0; m < 4; ++m)
#pragma unroll
      for (int r = 0; r < 4; ++r)
        s += __builtin_amdgcn_exp2f(acc[m][n][r] * ESCALE);
    s += __shfl_xor(s, 16);
    s += __shfl_xor(s, 32);
    if (lane < 16) redsum[wr * 128 + wc * 64 + n * 16 + lr] = s;
  }
  __syncthreads();
  if (tid < 128)
    colsum_part[(size_t)rb * NN + cb * 128 + tid] =
        redsum[tid] + redsum[128 + tid] + redsum[256 + tid] + redsum[384 + tid];
}

// ---------------- fused reductions: thread per output, coalesced ----------------
__global__ void reduce_both_kernel(const float* __restrict__ rowmax_part,
                                   const float* __restrict__ colsum_part,
                                   float* __restrict__ out, float* __restrict__ inv_s) {
  const int g = blockIdx.x * 256 + threadIdx.x;   // [0, 16384)
  if (g < 8192) {
    float m = -3.4e38f;
#pragma unroll
    for (int b = 0; b < 64; ++b) m = fmaxf(m, rowmax_part[(size_t)b * NN + g]);
    out[256 + g] = m;
  } else {
    const int j = g - 8192;
    float s = 0.f;
#pragma unroll
    for (int b = 0; b < 32; ++b) s += colsum_part[(size_t)b * NN + j];
    inv_s[j] = 1.0f / s;
  }
}

// ---------------- warped color partials ----------------
// 128 blocks = 32 k-octets x 4 j-quarters. Thread t: kk = t&7, j-stream t>>3.
// 8 adjacent lanes share j -> ynb reads are 16B-contiguous per 8 lanes.
__global__ void warped_kernel(const float* __restrict__ corr_top, const float* __restrict__ inv_s,
                              const ushort* __restrict__ ynb, float* __restrict__ wpart) {
  const int b = blockIdx.x;
  const int kb = b & 31, jb = b >> 5;
  const int k0 = kb * 8;
  const int t = threadIdx.x;
  const int kk = t & 7, js = t >> 3;     // js 0..31
  const int jbase = jb * 2048 + js;
  float p = 0.f;
#pragma unroll 4
  for (int i = 0; i < 64; ++i) {
    const int j = jbase + 32 * i;
    float c = corr_top[(size_t)(k0 + kk) * NN + j];
    float yv = __uint_as_float((unsigned)ynb[(size_t)j * CC + k0 + kk] << 16);
    p += __builtin_amdgcn_exp2f(c * ESCALE) * inv_s[j] * yv;
  }
  // reduce the 8 j-streams within each wave (kk preserved: masks 8,16,32)
  p += __shfl_xor(p, 8);
  p += __shfl_xor(p, 16);
  p += __shfl_xor(p, 32);
  __shared__ float lw[4][8];
  const int lane = t & 63, wid = t >> 6;
  if (lane < 8) lw[wid][lane] = p;
  __syncthreads();
  if (t < 8) wpart[jb * 256 + k0 + t] = lw[0][t] + lw[1][t] + lw[2][t] + lw[3][t];
}

__global__ void warpedfin_kernel(const float* __restrict__ wpart, float* __restrict__ out) {
  const int k = threadIdx.x;
  out[k] = wpart[k] + wpart[256 + k] + wpart[512 + k] + wpart[768 + k];
}

extern "C" void kernel_launch(void* const* d_in, const int* in_sizes, int n_in,
                              void* d_out, int out_size, void* d_ws, size_t ws_size,
                              hipStream_t stream) {
  const float* x = (const float*)d_in[0];
  const float* y = (const float*)d_in[1];
  float* out = (float*)d_out;
  char* ws = (char*)d_ws;

  ushort* xnb        = (ushort*)(ws);                        // 4 MB
  ushort* ynb        = (ushort*)(ws + (4u << 20));           // 4 MB
  float*  corr_top   = (float*)(ws + (8u << 20));            // 8 MB
  float*  rowmax_prt = (float*)(ws + (16u << 20));           // 2 MB
  float*  colsum_prt = (float*)(ws + (18u << 20));           // 1 MB
  float*  part       = (float*)(ws + (20u << 20));           // 512 KB (reused as wpart)
  float*  inv_n      = (float*)(ws + (20u << 20) + 524288);  // 2 KB
  float*  inv_s      = (float*)(ws + (20u << 20) + 524288 + 4096); // 32 KB

  colsumsq_kernel<<<512, 256, 0, stream>>>(x, y, part);
  finnorm_kernel<<<128, 256, 0, stream>>>(part, inv_n);
  normconv_kernel<<<4096, 256, 0, stream>>>(x, y, inv_n, xnb, ynb);
  gemm_corr_kernel<<<dim3(64, 32), 512, 0, stream>>>(xnb, ynb, corr_top, rowmax_prt, colsum_prt);
  reduce_both_kernel<<<64, 256, 0, stream>>>(rowmax_prt, colsum_prt, out, inv_s);
  warped_kernel<<<128, 256, 0, stream>>>(corr_top, inv_s, ynb, part);
  warpedfin_kernel<<<1, 256, 0, stream>>>(part, out);
}